// Round 6
// baseline (519.543 us; speedup 1.0000x reference)
//
#include <hip/hip_runtime.h>
#include <hip/hip_bf16.h>
#include <math.h>

// Problem constants (B,T,S,DQ,DKV,DOUT fixed by the reference)
#define B_SZ 2
#define T_SZ 1024
#define S_SZ 1024
#define NQ 16
#define NKV 4
#define HD 128
#define DQ 2048
#define DKV 2048
#define DOUT 2048

typedef _Float16 half8 __attribute__((ext_vector_type(8)));
typedef float f32x4 __attribute__((ext_vector_type(4)));

// ---- dtype-generic 8-element load -> half8 (fp32 inputs converted) --------
__device__ inline half8 load8_f16(const float* p) {
    float4 a = *reinterpret_cast<const float4*>(p);
    float4 b = *reinterpret_cast<const float4*>(p + 4);
    half8 r;
    r[0] = (_Float16)a.x; r[1] = (_Float16)a.y; r[2] = (_Float16)a.z; r[3] = (_Float16)a.w;
    r[4] = (_Float16)b.x; r[5] = (_Float16)b.y; r[6] = (_Float16)b.z; r[7] = (_Float16)b.w;
    return r;
}
__device__ inline half8 load8_f16(const _Float16* p) {
    return *reinterpret_cast<const half8*>(p);
}

// ---------------------------------------------------------------------------
// 64x64 GEMM (fp16 MFMA, fp32 acc): C[M,N] = A[M,K]*B[K,N]; row-major.
// Used for the narrow K/V projections (keeps grid at 256 blocks).
// LDS rows padded to 40 el (20 words): b128 frag reads/stores land uniform
// 8-per-4-word-window = structural optimum; B transpose staging 4-way only.
// ---------------------------------------------------------------------------
template <typename TA, typename TB, typename TC>
__global__ __launch_bounds__(256) void gemm_nn(const TA* __restrict__ A,
                                               const TB* __restrict__ B,
                                               TC* __restrict__ C,
                                               int M, int N, int K) {
    __shared__ __align__(16) _Float16 As[64][40];
    __shared__ __align__(16) _Float16 Bs[64][40];   // transposed: Bs[n][k]
    const int tid = threadIdx.x;
    const int lane = tid & 63, w = tid >> 6;
    const int quad = lane >> 4, l16 = lane & 15;
    const int bm = blockIdx.y * 64, bn = blockIdx.x * 64;
    const int wm = (w >> 1) * 32, wn = (w & 1) * 32;

    f32x4 acc[2][2];
    #pragma unroll
    for (int i = 0; i < 2; ++i)
        #pragma unroll
        for (int j = 0; j < 2; ++j)
            acc[i][j] = (f32x4){0.f, 0.f, 0.f, 0.f};

    const int ar = tid >> 2, akc = (tid & 3) * 8;   // A stage: row, k-chunk
    const int bkk = tid & 31, bnc = (tid >> 5) * 8; // B stage: k (lane-major), n-chunk

    for (int k0 = 0; k0 < K; k0 += 32) {
        __syncthreads();
        *reinterpret_cast<half8*>(&As[ar][akc]) =
            load8_f16(&A[(size_t)(bm + ar) * K + k0 + akc]);
        half8 bv = load8_f16(&B[(size_t)(k0 + bkk) * N + bn + bnc]);
        #pragma unroll
        for (int j = 0; j < 8; ++j) Bs[bnc + j][bkk] = bv[j];
        __syncthreads();

        half8 af0 = *reinterpret_cast<const half8*>(&As[wm + l16][quad * 8]);
        half8 af1 = *reinterpret_cast<const half8*>(&As[wm + 16 + l16][quad * 8]);
        half8 bf0 = *reinterpret_cast<const half8*>(&Bs[wn + l16][quad * 8]);
        half8 bf1 = *reinterpret_cast<const half8*>(&Bs[wn + 16 + l16][quad * 8]);
        acc[0][0] = __builtin_amdgcn_mfma_f32_16x16x32_f16(af0, bf0, acc[0][0], 0, 0, 0);
        acc[0][1] = __builtin_amdgcn_mfma_f32_16x16x32_f16(af0, bf1, acc[0][1], 0, 0, 0);
        acc[1][0] = __builtin_amdgcn_mfma_f32_16x16x32_f16(af1, bf0, acc[1][0], 0, 0, 0);
        acc[1][1] = __builtin_amdgcn_mfma_f32_16x16x32_f16(af1, bf1, acc[1][1], 0, 0, 0);
    }

    #pragma unroll
    for (int mi = 0; mi < 2; ++mi)
        #pragma unroll
        for (int ni = 0; ni < 2; ++ni)
            #pragma unroll
            for (int r = 0; r < 4; ++r)
                C[(size_t)(bm + wm + 16 * mi + quad * 4 + r) * N + bn + wn + 16 * ni + l16] =
                    (TC)acc[mi][ni][r];
}

// ---------------------------------------------------------------------------
// 128x128 GEMM (fp16 MFMA, fp32 acc), BK=32, 4 waves each owning 64x64
// (4x4 MFMA tiles, 16 MFMA per k-step per wave — m93 ladder structure).
// Used for the two 2048^3 GEMMs (Q-proj, out-proj).
// ---------------------------------------------------------------------------
template <typename TA, typename TB, typename TC>
__global__ __launch_bounds__(256) void gemm_big(const TA* __restrict__ A,
                                                const TB* __restrict__ B,
                                                TC* __restrict__ C,
                                                int M, int N, int K) {
    __shared__ __align__(16) _Float16 As[128][40];
    __shared__ __align__(16) _Float16 Bs[128][40];  // transposed: Bs[n][k]
    const int tid = threadIdx.x;
    const int lane = tid & 63, w = tid >> 6;
    const int quad = lane >> 4, l16 = lane & 15;
    const int bm = blockIdx.y * 128, bn = blockIdx.x * 128;
    const int wm = (w >> 1) * 64, wn = (w & 1) * 64;

    f32x4 acc[4][4];
    #pragma unroll
    for (int i = 0; i < 4; ++i)
        #pragma unroll
        for (int j = 0; j < 4; ++j)
            acc[i][j] = (f32x4){0.f, 0.f, 0.f, 0.f};

    const int ar = tid >> 1, akc = (tid & 1) * 16;   // A: 128 rows, 2 k-chunks
    const int bkk = tid & 31, bnc = (tid >> 5) * 16; // B: k lane-major, 8 n-chunks

    for (int k0 = 0; k0 < K; k0 += 32) {
        __syncthreads();
        *reinterpret_cast<half8*>(&As[ar][akc]) =
            load8_f16(&A[(size_t)(bm + ar) * K + k0 + akc]);
        *reinterpret_cast<half8*>(&As[ar][akc + 8]) =
            load8_f16(&A[(size_t)(bm + ar) * K + k0 + akc + 8]);
        half8 bv0 = load8_f16(&B[(size_t)(k0 + bkk) * N + bn + bnc]);
        half8 bv1 = load8_f16(&B[(size_t)(k0 + bkk) * N + bn + bnc + 8]);
        #pragma unroll
        for (int j = 0; j < 8; ++j) {
            Bs[bnc + j][bkk]     = bv0[j];
            Bs[bnc + 8 + j][bkk] = bv1[j];
        }
        __syncthreads();

        half8 af[4], bf[4];
        #pragma unroll
        for (int i = 0; i < 4; ++i) {
            af[i] = *reinterpret_cast<const half8*>(&As[wm + 16 * i + l16][quad * 8]);
            bf[i] = *reinterpret_cast<const half8*>(&Bs[wn + 16 * i + l16][quad * 8]);
        }
        #pragma unroll
        for (int mi = 0; mi < 4; ++mi)
            #pragma unroll
            for (int ni = 0; ni < 4; ++ni)
                acc[mi][ni] = __builtin_amdgcn_mfma_f32_16x16x32_f16(af[mi], bf[ni], acc[mi][ni], 0, 0, 0);
    }

    #pragma unroll
    for (int mi = 0; mi < 4; ++mi)
        #pragma unroll
        for (int ni = 0; ni < 4; ++ni)
            #pragma unroll
            for (int r = 0; r < 4; ++r)
                C[(size_t)(bm + wm + 16 * mi + quad * 4 + r) * N + bn + wn + 16 * ni + l16] =
                    (TC)acc[mi][ni][r];
}

// ---------------------------------------------------------------------------
// RoPE in-place on fp16 x:(B,L,N,HD), fp32 math. half=64. ts = 10000^(h/64).
// ---------------------------------------------------------------------------
__global__ __launch_bounds__(256) void rope_kernel(_Float16* __restrict__ x,
                                                   const int* __restrict__ pos,
                                                   int N) {
    size_t idx = (size_t)blockIdx.x * 256 + threadIdx.x;
    int h = (int)(idx & 63);
    size_t g = idx >> 6;            // (b*L + l)*N + n
    size_t bl = g / (size_t)N;      // b*L + l
    float p = (float)pos[bl];
    float ts = powf(10000.f, (float)h * (1.f / 64.f));
    float ang = p / ts;
    float s = sinf(ang), c = cosf(ang);
    size_t base = g * HD;
    float x1 = (float)x[base + h];
    float x2 = (float)x[base + h + 64];
    x[base + h]      = (_Float16)(x1 * c - x2 * s);
    x[base + h + 64] = (_Float16)(x2 * c + x1 * s);
}

// ---------------------------------------------------------------------------
// Flash attention (non-causal, scale=1.0, GQA group=4), all fp16, fp32 acc.
// Q,K,V fp16 (RoPE pre-applied); O fp16.
// Block = 256 thr (4 waves); block owns 64 q-rows of one (b, q-head).
// LDS: Ks 17.4K + Vt 18.4K + Ps 2K = ~38 KB -> 4 blocks/CU.
// ---------------------------------------------------------------------------
__global__ __launch_bounds__(256) void attn_kernel(const _Float16* __restrict__ Q,
                                                   const _Float16* __restrict__ K,
                                                   const _Float16* __restrict__ V,
                                                   _Float16* __restrict__ O) {
    __shared__ __align__(16) _Float16 Ks[64][136];
    __shared__ __align__(16) _Float16 Vt[128][72];
    __shared__ __align__(16) _Float16 Ps[4][16][32];
    const int tid = threadIdx.x, lane = tid & 63, w = tid >> 6;
    const int quad = lane >> 4, l16 = lane & 15;
    const int blk = blockIdx.x;
    const int t0 = (blk & 15) * 64;       // T/64 = 16 q-tiles
    const int n  = (blk >> 4) & 15;       // q head
    const int b  = blk >> 8;              // batch
    const int kn = n >> 2;                // kv head (G=4)

    // Q fragments for this wave's 16 rows, in registers.
    half8 qf[4];
    #pragma unroll
    for (int kh = 0; kh < 4; ++kh)
        qf[kh] = load8_f16(&Q[(((size_t)b * T_SZ + t0 + w * 16 + l16) * NQ + n) * HD + kh * 32 + quad * 8]);

    f32x4 o_acc[8];
    #pragma unroll
    for (int i = 0; i < 8; ++i) o_acc[i] = (f32x4){0.f, 0.f, 0.f, 0.f};
    float m_row[4] = {-1e30f, -1e30f, -1e30f, -1e30f};
    float l_row[4] = {0.f, 0.f, 0.f, 0.f};

    for (int s0 = 0; s0 < S_SZ; s0 += 64) {
        __syncthreads();
        #pragma unroll
        for (int i = 0; i < 4; ++i) {
            int e = tid + i * 256;
            // K: row-major staging, vector b128 writes
            int r = e >> 4, c = (e & 15) * 8;
            *reinterpret_cast<half8*>(&Ks[r][c]) =
                load8_f16(&K[(((size_t)b * S_SZ + s0 + r) * NKV + kn) * HD + c]);
            // V: transpose staging, s-lane-major (conflict-free writes)
            int vs = e & 63, vc = (e >> 6) * 8;
            half8 vv = load8_f16(&V[(((size_t)b * S_SZ + s0 + vs) * NKV + kn) * HD + vc]);
            #pragma unroll
            for (int j = 0; j < 8; ++j) Vt[vc + j][vs] = vv[j];
        }
        __syncthreads();

        #pragma unroll
        for (int sc = 0; sc < 2; ++sc) {
            // ---- scores for 32 s-columns (two 16-wide MFMA tiles) ----
            f32x4 sf[2];
            #pragma unroll
            for (int j2 = 0; j2 < 2; ++j2) {
                f32x4 sa = (f32x4){0.f, 0.f, 0.f, 0.f};
                #pragma unroll
                for (int kh = 0; kh < 4; ++kh) {
                    half8 bk = *reinterpret_cast<const half8*>(
                        &Ks[sc * 32 + j2 * 16 + l16][kh * 32 + quad * 8]);
                    sa = __builtin_amdgcn_mfma_f32_16x16x32_f16(qf[kh], bk, sa, 0, 0, 0);
                }
                sf[j2] = sa;
            }
            // ---- online softmax (row = quad*4+r, reduce across 16 lanes) ----
            float alpha[4];
            #pragma unroll
            for (int r = 0; r < 4; ++r) {
                float mc = fmaxf(sf[0][r], sf[1][r]);
                #pragma unroll
                for (int off = 1; off < 16; off <<= 1)
                    mc = fmaxf(mc, __shfl_xor(mc, off, 64));
                float mn = fmaxf(m_row[r], mc);
                alpha[r] = fminf(expf(m_row[r] - mn), 1.f);
                m_row[r] = mn;
                float p0 = fminf(expf(sf[0][r] - mn), 1.f);
                float p1 = fminf(expf(sf[1][r] - mn), 1.f);
                sf[0][r] = p0; sf[1][r] = p1;
                float rs = p0 + p1;
                #pragma unroll
                for (int off = 1; off < 16; off <<= 1)
                    rs += __shfl_xor(rs, off, 64);
                l_row[r] = l_row[r] * alpha[r] + rs;
            }
            #pragma unroll
            for (int ht = 0; ht < 8; ++ht)
                #pragma unroll
                for (int r = 0; r < 4; ++r)
                    o_acc[ht][r] *= alpha[r];
            // ---- P: C-layout -> A-layout via per-wave LDS slice ----
            #pragma unroll
            for (int r = 0; r < 4; ++r) {
                Ps[w][quad * 4 + r][l16]      = (_Float16)sf[0][r];
                Ps[w][quad * 4 + r][16 + l16] = (_Float16)sf[1][r];
            }
            __builtin_amdgcn_wave_barrier();
            half8 ap = *reinterpret_cast<const half8*>(&Ps[w][l16][quad * 8]);
            __builtin_amdgcn_wave_barrier();
            // ---- O += P @ V ----
            #pragma unroll
            for (int ht = 0; ht < 8; ++ht) {
                half8 bv = *reinterpret_cast<const half8*>(&Vt[ht * 16 + l16][sc * 32 + quad * 8]);
                o_acc[ht] = __builtin_amdgcn_mfma_f32_16x16x32_f16(ap, bv, o_acc[ht], 0, 0, 0);
            }
        }
    }

    float inv_l[4];
    #pragma unroll
    for (int r = 0; r < 4; ++r) inv_l[r] = 1.f / fmaxf(l_row[r], 1e-30f);
    #pragma unroll
    for (int ht = 0; ht < 8; ++ht)
        #pragma unroll
        for (int r = 0; r < 4; ++r)
            O[(((size_t)b * T_SZ + t0 + w * 16 + quad * 4 + r) * NQ + n) * HD + ht * 16 + l16] =
                (_Float16)(o_acc[ht][r] * inv_l[r]);
}

// ---------------------------------------------------------------------------
extern "C" void kernel_launch(void* const* d_in, const int* in_sizes, int n_in,
                              void* d_out, int out_size, void* d_ws, size_t ws_size,
                              hipStream_t stream) {
    const float* Xq   = (const float*)d_in[0];   // (B,T,DQ)
    const float* Xkv  = (const float*)d_in[1];   // (B,S,DKV)
    const int*   qpos = (const int*)d_in[2];     // (B,T)
    const int*   kpos = (const int*)d_in[3];     // (B,S)
    const float* Wq   = (const float*)d_in[4];   // (DQ, NQ*HD)
    const float* Wk   = (const float*)d_in[5];   // (DKV, NKV*HD)
    const float* Wv   = (const float*)d_in[6];   // (DKV, NKV*HD)
    const float* Wo   = (const float*)d_in[7];   // (NQ*HD, DOUT)
    float* out = (float*)d_out;                  // (B,T,DOUT) fp32

    // workspace (fp16): Q 8.4MB | K 2.1MB | V 2.1MB | attn 8.4MB = 21 MB
    _Float16* Qh = (_Float16*)d_ws;
    _Float16* Kh = Qh + (size_t)B_SZ * T_SZ * NQ * HD;
    _Float16* Vh = Kh + (size_t)B_SZ * S_SZ * NKV * HD;
    _Float16* Ah = Vh + (size_t)B_SZ * S_SZ * NKV * HD;

    dim3 blk(256);
    // Q projection: 2048^3, 128-tile
    gemm_big<float, float, _Float16><<<dim3((NQ * HD) / 128, (B_SZ * T_SZ) / 128), blk, 0, stream>>>(
        Xq, Wq, Qh, B_SZ * T_SZ, NQ * HD, DQ);
    // K,V projections: N=512, 64-tile (256 blocks)
    gemm_nn<float, float, _Float16><<<dim3((NKV * HD) / 64, (B_SZ * S_SZ) / 64), blk, 0, stream>>>(
        Xkv, Wk, Kh, B_SZ * S_SZ, NKV * HD, DKV);
    gemm_nn<float, float, _Float16><<<dim3((NKV * HD) / 64, (B_SZ * S_SZ) / 64), blk, 0, stream>>>(
        Xkv, Wv, Vh, B_SZ * S_SZ, NKV * HD, DKV);
    // RoPE on q and k (fp16 storage, fp32 math)
    rope_kernel<<<(B_SZ * T_SZ * NQ * 64) / 256, blk, 0, stream>>>(Qh, qpos, NQ);
    rope_kernel<<<(B_SZ * S_SZ * NKV * 64) / 256, blk, 0, stream>>>(Kh, kpos, NKV);
    // GQA flash attention -> attn fp16 (B,T,NQ,HD)
    attn_kernel<<<B_SZ * NQ * (T_SZ / 64), blk, 0, stream>>>(Qh, Kh, Vh, Ah);
    // output projection: 2048^3, 128-tile, fp32 out
    gemm_big<_Float16, float, float><<<dim3(DOUT / 128, (B_SZ * T_SZ) / 128), blk, 0, stream>>>(
        Ah, Wo, out, B_SZ * T_SZ, DOUT, NQ * HD);
}

// Round 7
// 371.984 us; speedup vs baseline: 1.3967x; 1.3967x over previous
//
#include <hip/hip_runtime.h>
#include <hip/hip_bf16.h>
#include <math.h>
#include <stdint.h>

// Problem constants (fixed by the reference)
#define B_SZ 2
#define T_SZ 1024
#define S_SZ 1024
#define NQ 16
#define NKV 4
#define HD 128
#define DQ 2048
#define DKV 2048
#define DOUT 2048

typedef _Float16 half8 __attribute__((ext_vector_type(8)));
typedef _Float16 half4 __attribute__((ext_vector_type(4)));
typedef float f32x4 __attribute__((ext_vector_type(4)));

__device__ __forceinline__ half8 load8_f16(const _Float16* p) {
    return *reinterpret_cast<const half8*>(p);
}

// ---- async global->LDS, 16 B per lane; lds base must be wave-uniform ------
__device__ __forceinline__ void stage16(const _Float16* g, _Float16* l, int lane) {
#if __has_builtin(__builtin_amdgcn_global_load_lds)
    __builtin_amdgcn_global_load_lds(
        (const __attribute__((address_space(1))) uint32_t*)g,
        (__attribute__((address_space(3))) uint32_t*)l, 16, 0, 0);
#else
    *reinterpret_cast<half8*>(l + lane * 8) = *reinterpret_cast<const half8*>(g);
#endif
}

// ---------------------------------------------------------------------------
// fp32 -> fp16 convert, 8 el/thread
// ---------------------------------------------------------------------------
__global__ __launch_bounds__(256) void convert_f32_f16(const float* __restrict__ in,
                                                       _Float16* __restrict__ out) {
    size_t i = ((size_t)blockIdx.x * 256 + threadIdx.x) * 8;
    float4 a = *reinterpret_cast<const float4*>(in + i);
    float4 b = *reinterpret_cast<const float4*>(in + i + 4);
    half8 r;
    r[0] = (_Float16)a.x; r[1] = (_Float16)a.y; r[2] = (_Float16)a.z; r[3] = (_Float16)a.w;
    r[4] = (_Float16)b.x; r[5] = (_Float16)b.y; r[6] = (_Float16)b.z; r[7] = (_Float16)b.w;
    *reinterpret_cast<half8*>(out + i) = r;
}

// ---------------------------------------------------------------------------
// Transpose + convert: in fp32 [R][C] -> out fp16 [C][R]. 64x64 LDS tiles.
// ---------------------------------------------------------------------------
__global__ __launch_bounds__(256) void transpose_f32_f16(const float* __restrict__ in,
                                                         _Float16* __restrict__ out,
                                                         int R, int C) {
    __shared__ _Float16 tile[64][72];
    const int tx = threadIdx.x & 15, ty = threadIdx.x >> 4;
    const int r0 = blockIdx.y * 64, c0 = blockIdx.x * 64;
    #pragma unroll
    for (int i = 0; i < 4; ++i) {
        int r = ty + i * 16;
        float4 v = *reinterpret_cast<const float4*>(&in[(size_t)(r0 + r) * C + c0 + tx * 4]);
        tile[r][tx * 4 + 0] = (_Float16)v.x;
        tile[r][tx * 4 + 1] = (_Float16)v.y;
        tile[r][tx * 4 + 2] = (_Float16)v.z;
        tile[r][tx * 4 + 3] = (_Float16)v.w;
    }
    __syncthreads();
    #pragma unroll
    for (int i = 0; i < 4; ++i) {
        int oc = ty + i * 16;   // out row = c0+oc
        half4 v;
        v[0] = tile[tx * 4 + 0][oc];
        v[1] = tile[tx * 4 + 1][oc];
        v[2] = tile[tx * 4 + 2][oc];
        v[3] = tile[tx * 4 + 3][oc];
        *reinterpret_cast<half4*>(&out[(size_t)(c0 + oc) * R + r0 + tx * 4]) = v;
    }
}

// ---------------------------------------------------------------------------
// GEMM C[M][N] = A[M][K] * Bt[N][K]^T, both fp16 row-major, fp32 acc.
// 4 waves; wave grid 2x2, wave tile (BM/2)x(BN/2).
// Staging: global_load_lds width-16 into fragment-order LDS:
//   element (kb, r) of a tile at lds[(kb*BT + r)*8] (BT = BM or BN).
//   Fragment ds_read_b128 bank = (r*4) mod 32 -> conflict-free.
//   Segment s (64 lanes x 16 B): li = s*64+lane, kb=li/BT, r=li%BT;
//   lds dst = s*1024 B + lane*16 B  == element li*8  (matches HW mapping).
// ---------------------------------------------------------------------------
template <int BM, int BN, typename TC>
__global__ __launch_bounds__(256) void gemm_tn(const _Float16* __restrict__ A,
                                               const _Float16* __restrict__ Bt,
                                               TC* __restrict__ C,
                                               int M, int N, int K) {
    constexpr int ASEG = BM / 16, BSEG = BN / 16, TSEG = ASEG + BSEG, PSEG = TSEG / 4;
    __shared__ __align__(16) _Float16 lds[(BM + BN) * 32];
    const int tid = threadIdx.x, lane = tid & 63, w = tid >> 6;
    const int quad = lane >> 4, l16 = lane & 15;
    const int bm = blockIdx.y * BM, bn = blockIdx.x * BN;
    constexpr int WM = BM / 2, WN = BN / 2, MI = WM / 16, NI = WN / 16;
    const int wm = (w >> 1) * WM, wn = (w & 1) * WN;

    // per-wave staging descriptors: segments w, w+4, ...
    const _Float16* gp[PSEG];
    _Float16* lp[PSEG];
    #pragma unroll
    for (int p = 0; p < PSEG; ++p) {
        int s = w + p * 4;
        if (s < ASEG) {
            int li = s * 64 + lane;
            int kb = li / BM, r = li % BM;
            gp[p] = A + (size_t)(bm + r) * K + kb * 8;
        } else {
            int li = (s - ASEG) * 64 + lane;
            int kb = li / BN, r = li % BN;
            gp[p] = Bt + (size_t)(bn + r) * K + kb * 8;
        }
        lp[p] = lds + s * 512;
    }

    f32x4 acc[MI][NI];
    #pragma unroll
    for (int i = 0; i < MI; ++i)
        #pragma unroll
        for (int j = 0; j < NI; ++j)
            acc[i][j] = (f32x4){0.f, 0.f, 0.f, 0.f};

    for (int k0 = 0; k0 < K; k0 += 32) {
        __syncthreads();
        #pragma unroll
        for (int p = 0; p < PSEG; ++p)
            stage16(gp[p] + k0, lp[p], lane);
        __syncthreads();

        half8 af[MI], bf[NI];
        #pragma unroll
        for (int i = 0; i < MI; ++i)
            af[i] = *reinterpret_cast<const half8*>(&lds[(quad * BM + wm + 16 * i + l16) * 8]);
        #pragma unroll
        for (int j = 0; j < NI; ++j)
            bf[j] = *reinterpret_cast<const half8*>(&lds[BM * 32 + (quad * BN + wn + 16 * j + l16) * 8]);
        #pragma unroll
        for (int i = 0; i < MI; ++i)
            #pragma unroll
            for (int j = 0; j < NI; ++j)
                acc[i][j] = __builtin_amdgcn_mfma_f32_16x16x32_f16(af[i], bf[j], acc[i][j], 0, 0, 0);
    }

    #pragma unroll
    for (int i = 0; i < MI; ++i)
        #pragma unroll
        for (int j = 0; j < NI; ++j)
            #pragma unroll
            for (int r = 0; r < 4; ++r)
                C[(size_t)(bm + wm + 16 * i + quad * 4 + r) * N + bn + wn + 16 * j + l16] =
                    (TC)acc[i][j][r];
}

// ---------------------------------------------------------------------------
// RoPE in-place on fp16, fp32 math. x rows indexed (bl, n): base = bl*rowStride + n*HD.
// ---------------------------------------------------------------------------
__global__ __launch_bounds__(256) void rope16(_Float16* __restrict__ x,
                                              const int* __restrict__ pos,
                                              int N, int rowStride) {
    size_t idx = (size_t)blockIdx.x * 256 + threadIdx.x;
    int h = (int)(idx & 63);
    size_t g = idx >> 6;
    int n = (int)(g % (size_t)N);
    size_t bl = g / (size_t)N;
    float p = (float)pos[bl];
    float ts = powf(10000.f, (float)h * (1.f / 64.f));
    float ang = p / ts;
    float s = sinf(ang), c = cosf(ang);
    size_t base = bl * (size_t)rowStride + (size_t)n * HD;
    float x1 = (float)x[base + h];
    float x2 = (float)x[base + h + 64];
    x[base + h]      = (_Float16)(x1 * c - x2 * s);
    x[base + h + 64] = (_Float16)(x2 * c + x1 * s);
}

// ---------------------------------------------------------------------------
// Flash attention (non-causal, scale=1.0, GQA group=4), all fp16, fp32 acc.
// Q:(B,T,NQ,HD) fp16; KV fused:(B,S,1024) fp16 — K at col kn*HD, V at 512+kn*HD.
// Block = 256 thr (4 waves); block owns 64 q-rows of one (b, q-head).
// ---------------------------------------------------------------------------
__global__ __launch_bounds__(256) void attn_kernel(const _Float16* __restrict__ Q,
                                                   const _Float16* __restrict__ KV,
                                                   _Float16* __restrict__ O) {
    __shared__ __align__(16) _Float16 Ks[64][136];
    __shared__ __align__(16) _Float16 Vt[128][72];
    __shared__ __align__(16) _Float16 Ps[4][16][32];
    const int tid = threadIdx.x, lane = tid & 63, w = tid >> 6;
    const int quad = lane >> 4, l16 = lane & 15;
    const int blk = blockIdx.x;
    const int t0 = (blk & 15) * 64;
    const int n  = (blk >> 4) & 15;
    const int b  = blk >> 8;
    const int kn = n >> 2;

    half8 qf[4];
    #pragma unroll
    for (int kh = 0; kh < 4; ++kh)
        qf[kh] = load8_f16(&Q[(((size_t)b * T_SZ + t0 + w * 16 + l16) * NQ + n) * HD + kh * 32 + quad * 8]);

    f32x4 o_acc[8];
    #pragma unroll
    for (int i = 0; i < 8; ++i) o_acc[i] = (f32x4){0.f, 0.f, 0.f, 0.f};
    float m_row[4] = {-1e30f, -1e30f, -1e30f, -1e30f};
    float l_row[4] = {0.f, 0.f, 0.f, 0.f};

    for (int s0 = 0; s0 < S_SZ; s0 += 64) {
        __syncthreads();
        #pragma unroll
        for (int i = 0; i < 4; ++i) {
            int e = tid + i * 256;
            int r = e >> 4, c = (e & 15) * 8;
            *reinterpret_cast<half8*>(&Ks[r][c]) =
                load8_f16(&KV[(size_t)(b * S_SZ + s0 + r) * 1024 + kn * HD + c]);
            int vs = e & 63, vc = (e >> 6) * 8;
            half8 vv = load8_f16(&KV[(size_t)(b * S_SZ + s0 + vs) * 1024 + 512 + kn * HD + vc]);
            #pragma unroll
            for (int j = 0; j < 8; ++j) Vt[vc + j][vs] = vv[j];
        }
        __syncthreads();

        #pragma unroll
        for (int sc = 0; sc < 2; ++sc) {
            f32x4 sf[2];
            #pragma unroll
            for (int j2 = 0; j2 < 2; ++j2) {
                f32x4 sa = (f32x4){0.f, 0.f, 0.f, 0.f};
                #pragma unroll
                for (int kh = 0; kh < 4; ++kh) {
                    half8 bk = *reinterpret_cast<const half8*>(
                        &Ks[sc * 32 + j2 * 16 + l16][kh * 32 + quad * 8]);
                    sa = __builtin_amdgcn_mfma_f32_16x16x32_f16(qf[kh], bk, sa, 0, 0, 0);
                }
                sf[j2] = sa;
            }
            float alpha[4];
            #pragma unroll
            for (int r = 0; r < 4; ++r) {
                float mc = fmaxf(sf[0][r], sf[1][r]);
                #pragma unroll
                for (int off = 1; off < 16; off <<= 1)
                    mc = fmaxf(mc, __shfl_xor(mc, off, 64));
                float mn = fmaxf(m_row[r], mc);
                alpha[r] = fminf(expf(m_row[r] - mn), 1.f);
                m_row[r] = mn;
                float p0 = fminf(expf(sf[0][r] - mn), 1.f);
                float p1 = fminf(expf(sf[1][r] - mn), 1.f);
                sf[0][r] = p0; sf[1][r] = p1;
                float rs = p0 + p1;
                #pragma unroll
                for (int off = 1; off < 16; off <<= 1)
                    rs += __shfl_xor(rs, off, 64);
                l_row[r] = l_row[r] * alpha[r] + rs;
            }
            #pragma unroll
            for (int ht = 0; ht < 8; ++ht)
                #pragma unroll
                for (int r = 0; r < 4; ++r)
                    o_acc[ht][r] *= alpha[r];
            #pragma unroll
            for (int r = 0; r < 4; ++r) {
                Ps[w][quad * 4 + r][l16]      = (_Float16)sf[0][r];
                Ps[w][quad * 4 + r][16 + l16] = (_Float16)sf[1][r];
            }
            __builtin_amdgcn_wave_barrier();
            half8 ap = *reinterpret_cast<const half8*>(&Ps[w][l16][quad * 8]);
            __builtin_amdgcn_wave_barrier();
            #pragma unroll
            for (int ht = 0; ht < 8; ++ht) {
                half8 bv = *reinterpret_cast<const half8*>(&Vt[ht * 16 + l16][sc * 32 + quad * 8]);
                o_acc[ht] = __builtin_amdgcn_mfma_f32_16x16x32_f16(ap, bv, o_acc[ht], 0, 0, 0);
            }
        }
    }

    float inv_l[4];
    #pragma unroll
    for (int r = 0; r < 4; ++r) inv_l[r] = 1.f / fmaxf(l_row[r], 1e-30f);
    #pragma unroll
    for (int ht = 0; ht < 8; ++ht)
        #pragma unroll
        for (int r = 0; r < 4; ++r)
            O[(((size_t)b * T_SZ + t0 + w * 16 + quad * 4 + r) * NQ + n) * HD + ht * 16 + l16] =
                (_Float16)(o_acc[ht][r] * inv_l[r]);
}

// ---------------------------------------------------------------------------
extern "C" void kernel_launch(void* const* d_in, const int* in_sizes, int n_in,
                              void* d_out, int out_size, void* d_ws, size_t ws_size,
                              hipStream_t stream) {
    const float* Xq   = (const float*)d_in[0];
    const float* Xkv  = (const float*)d_in[1];
    const int*   qpos = (const int*)d_in[2];
    const int*   kpos = (const int*)d_in[3];
    const float* Wq   = (const float*)d_in[4];   // (2048, 2048)
    const float* Wk   = (const float*)d_in[5];   // (2048, 512)
    const float* Wv   = (const float*)d_in[6];   // (2048, 512)
    const float* Wo   = (const float*)d_in[7];   // (2048, 2048)
    float* out = (float*)d_out;

    // workspace packing (37.75 MB) with lifetime-based reuse:
    //   B0: Xq16   -> Ah (attn out)
    //   B1: Xkv16  -> WoT (transposed after KV-proj)
    //   B2: WqT    -> KVh (written by KV-proj after WqT's last read)
    //   B3: WkvT (4.2 MB)   B4: Qh
    const size_t SZ8 = 8388608;   // 4.2M fp16 elements
    uint8_t* ws = (uint8_t*)d_ws;
    _Float16* Xq16  = (_Float16*)(ws);
    _Float16* Xkv16 = (_Float16*)(ws + SZ8);
    _Float16* WqT   = (_Float16*)(ws + 2 * SZ8);
    _Float16* WkvT  = (_Float16*)(ws + 3 * SZ8);
    _Float16* Qh    = (_Float16*)(ws + 3 * SZ8 + 4194304);
    _Float16* Ah  = Xq16;
    _Float16* WoT = Xkv16;
    _Float16* KVh = WqT;

    dim3 blk(256);
    // pre-passes: fp16 conversion + weight transposes (B^T row-major)
    convert_f32_f16<<<2048, blk, 0, stream>>>(Xq, Xq16);
    convert_f32_f16<<<2048, blk, 0, stream>>>(Xkv, Xkv16);
    transpose_f32_f16<<<dim3(32, 32), blk, 0, stream>>>(Wq, WqT, 2048, 2048);
    transpose_f32_f16<<<dim3(8, 32), blk, 0, stream>>>(Wk, WkvT, 2048, 512);
    transpose_f32_f16<<<dim3(8, 32), blk, 0, stream>>>(Wv, WkvT + (size_t)512 * 2048, 2048, 512);
    // Q projection: 2048x2048x2048, BM=128/BN=64 -> 512 blocks (2/CU)
    gemm_tn<128, 64, _Float16><<<dim3(32, 16), blk, 0, stream>>>(
        Xq16, WqT, Qh, B_SZ * T_SZ, NQ * HD, DQ);
    // K+V fused projection: 2048x1024x2048, BM=BN=64 -> 512 blocks
    gemm_tn<64, 64, _Float16><<<dim3(16, 32), blk, 0, stream>>>(
        Xkv16, WkvT, KVh, B_SZ * S_SZ, 1024, DKV);
    // Wo transpose into Xkv16's slot (dead after KV-proj)
    transpose_f32_f16<<<dim3(32, 32), blk, 0, stream>>>(Wo, WoT, 2048, 2048);
    // RoPE on Q and on K-half of KV
    rope16<<<8192, blk, 0, stream>>>(Qh, qpos, NQ, NQ * HD);
    rope16<<<2048, blk, 0, stream>>>(KVh, kpos, NKV, 1024);
    // GQA flash attention -> Ah (B,T,NQ,HD) fp16  (Xq16 slot, dead)
    attn_kernel<<<512, blk, 0, stream>>>(Qh, KVh, Ah);
    // output projection -> fp32 out
    gemm_tn<128, 64, float><<<dim3(32, 16), blk, 0, stream>>>(
        Ah, WoT, out, B_SZ * T_SZ, DOUT, NQ * HD);
}

// Round 8
// 350.971 us; speedup vs baseline: 1.4803x; 1.0599x over previous
//
#include <hip/hip_runtime.h>
#include <hip/hip_bf16.h>
#include <math.h>
#include <stdint.h>

// Problem constants (fixed by the reference)
#define B_SZ 2
#define T_SZ 1024
#define S_SZ 1024
#define NQ 16
#define NKV 4
#define HD 128
#define DQ 2048
#define DKV 2048
#define DOUT 2048

typedef _Float16 half8 __attribute__((ext_vector_type(8)));
typedef _Float16 half4 __attribute__((ext_vector_type(4)));
typedef float f32x4 __attribute__((ext_vector_type(4)));

__device__ __forceinline__ half8 load8_f16(const _Float16* p) {
    return *reinterpret_cast<const half8*>(p);
}

// ---- async global->LDS, 16 B per lane; lds base must be wave-uniform ------
__device__ __forceinline__ void stage16(const _Float16* g, _Float16* l, int lane) {
#if __has_builtin(__builtin_amdgcn_global_load_lds)
    __builtin_amdgcn_global_load_lds(
        (const __attribute__((address_space(1))) uint32_t*)g,
        (__attribute__((address_space(3))) uint32_t*)l, 16, 0, 0);
#else
    *reinterpret_cast<half8*>(l + lane * 8) = *reinterpret_cast<const half8*>(g);
#endif
}

// ---------------------------------------------------------------------------
// fp32 -> fp16 convert, 8 el/thread
// ---------------------------------------------------------------------------
__global__ __launch_bounds__(256) void convert_f32_f16(const float* __restrict__ in,
                                                       _Float16* __restrict__ out) {
    size_t i = ((size_t)blockIdx.x * 256 + threadIdx.x) * 8;
    float4 a = *reinterpret_cast<const float4*>(in + i);
    float4 b = *reinterpret_cast<const float4*>(in + i + 4);
    half8 r;
    r[0] = (_Float16)a.x; r[1] = (_Float16)a.y; r[2] = (_Float16)a.z; r[3] = (_Float16)a.w;
    r[4] = (_Float16)b.x; r[5] = (_Float16)b.y; r[6] = (_Float16)b.z; r[7] = (_Float16)b.w;
    *reinterpret_cast<half8*>(out + i) = r;
}

// ---------------------------------------------------------------------------
// Transpose + convert: in fp32 [R][C] -> out fp16 [C][R]. 64x64 LDS tiles.
// ---------------------------------------------------------------------------
__global__ __launch_bounds__(256) void transpose_f32_f16(const float* __restrict__ in,
                                                         _Float16* __restrict__ out,
                                                         int R, int C) {
    __shared__ _Float16 tile[64][72];
    const int tx = threadIdx.x & 15, ty = threadIdx.x >> 4;
    const int r0 = blockIdx.y * 64, c0 = blockIdx.x * 64;
    #pragma unroll
    for (int i = 0; i < 4; ++i) {
        int r = ty + i * 16;
        float4 v = *reinterpret_cast<const float4*>(&in[(size_t)(r0 + r) * C + c0 + tx * 4]);
        tile[r][tx * 4 + 0] = (_Float16)v.x;
        tile[r][tx * 4 + 1] = (_Float16)v.y;
        tile[r][tx * 4 + 2] = (_Float16)v.z;
        tile[r][tx * 4 + 3] = (_Float16)v.w;
    }
    __syncthreads();
    #pragma unroll
    for (int i = 0; i < 4; ++i) {
        int oc = ty + i * 16;
        half4 v;
        v[0] = tile[tx * 4 + 0][oc];
        v[1] = tile[tx * 4 + 1][oc];
        v[2] = tile[tx * 4 + 2][oc];
        v[3] = tile[tx * 4 + 3][oc];
        *reinterpret_cast<half4*>(&out[(size_t)(c0 + oc) * R + r0 + tx * 4]) = v;
    }
}

// ---------------------------------------------------------------------------
// GEMM tile body: C[bm:bm+BM][bn:bn+BN] (+)= A[.][kbeg:kend] * Bt[.][kbeg:kend]^T
// A,Bt fp16 row-major with row stride K. 4 waves, wave grid 2x2.
// Staging via global_load_lds width-16 into fragment-order LDS (conflict-free).
// ---------------------------------------------------------------------------
template <int BM, int BN, bool ATOMIC, typename TC>
__device__ __forceinline__ void gemm_tile(const _Float16* __restrict__ A,
                                          const _Float16* __restrict__ Bt,
                                          TC* __restrict__ C,
                                          int N, int K, int kbeg, int kend,
                                          int bm, int bn, _Float16* lds) {
    constexpr int ASEG = BM / 16, BSEG = BN / 16, TSEG = ASEG + BSEG, PSEG = TSEG / 4;
    const int tid = threadIdx.x, lane = tid & 63, w = tid >> 6;
    const int quad = lane >> 4, l16 = lane & 15;
    constexpr int WM = BM / 2, WN = BN / 2, MI = WM / 16, NI = WN / 16;
    const int wm = (w >> 1) * WM, wn = (w & 1) * WN;

    const _Float16* gp[PSEG];
    _Float16* lp[PSEG];
    #pragma unroll
    for (int p = 0; p < PSEG; ++p) {
        int s = w + p * 4;
        if (s < ASEG) {
            int li = s * 64 + lane;
            int kb = li / BM, r = li % BM;
            gp[p] = A + (size_t)(bm + r) * K + kbeg + kb * 8;
        } else {
            int li = (s - ASEG) * 64 + lane;
            int kb = li / BN, r = li % BN;
            gp[p] = Bt + (size_t)(bn + r) * K + kbeg + kb * 8;
        }
        lp[p] = lds + s * 512;
    }

    f32x4 acc[MI][NI];
    #pragma unroll
    for (int i = 0; i < MI; ++i)
        #pragma unroll
        for (int j = 0; j < NI; ++j)
            acc[i][j] = (f32x4){0.f, 0.f, 0.f, 0.f};

    const int nsteps = (kend - kbeg) >> 5;
    for (int it = 0; it < nsteps; ++it) {
        const int ko = it * 32;
        __syncthreads();
        #pragma unroll
        for (int p = 0; p < PSEG; ++p)
            stage16(gp[p] + ko, lp[p], lane);
        __syncthreads();

        half8 af[MI], bf[NI];
        #pragma unroll
        for (int i = 0; i < MI; ++i)
            af[i] = *reinterpret_cast<const half8*>(&lds[(quad * BM + wm + 16 * i + l16) * 8]);
        #pragma unroll
        for (int j = 0; j < NI; ++j)
            bf[j] = *reinterpret_cast<const half8*>(&lds[BM * 32 + (quad * BN + wn + 16 * j + l16) * 8]);
        #pragma unroll
        for (int i = 0; i < MI; ++i)
            #pragma unroll
            for (int j = 0; j < NI; ++j)
                acc[i][j] = __builtin_amdgcn_mfma_f32_16x16x32_f16(af[i], bf[j], acc[i][j], 0, 0, 0);
    }

    #pragma unroll
    for (int i = 0; i < MI; ++i)
        #pragma unroll
        for (int j = 0; j < NI; ++j)
            #pragma unroll
            for (int r = 0; r < 4; ++r) {
                size_t idx = (size_t)(bm + wm + 16 * i + quad * 4 + r) * N + bn + wn + 16 * j + l16;
                if (ATOMIC) atomicAdd((float*)&C[idx], acc[i][j][r]);
                else        C[idx] = (TC)acc[i][j][r];
            }
}

// Fused Q-proj + KV-proj: blocks [0,512) -> Q (N=2048); [512,768) -> KV (N=1024).
__global__ __launch_bounds__(256) void proj_fused(const _Float16* __restrict__ Xq,
                                                  const _Float16* __restrict__ WqT,
                                                  _Float16* __restrict__ Qh,
                                                  const _Float16* __restrict__ Xkv,
                                                  const _Float16* __restrict__ WkvT,
                                                  _Float16* __restrict__ KVh) {
    __shared__ __align__(16) _Float16 lds[(128 + 64) * 32];
    int bx = blockIdx.x;
    if (bx < 512) {
        gemm_tile<128, 64, false, _Float16>(Xq, WqT, Qh, 2048, 2048, 0, 2048,
                                            (bx & 15) * 128, (bx >> 4) * 64, lds);
    } else {
        bx -= 512;
        gemm_tile<128, 64, false, _Float16>(Xkv, WkvT, KVh, 1024, 2048, 0, 2048,
                                            (bx & 15) * 128, (bx >> 4) * 64, lds);
    }
}

// Out-proj, split-K=2, fp32 atomic accumulate into pre-zeroed C.
__global__ __launch_bounds__(256) void gemm_splitk(const _Float16* __restrict__ A,
                                                   const _Float16* __restrict__ Bt,
                                                   float* __restrict__ C) {
    __shared__ __align__(16) _Float16 lds[(128 + 64) * 32];
    const int bx = blockIdx.x;
    const int tile = bx & 511, kk = bx >> 9;
    gemm_tile<128, 64, true, float>(A, Bt, C, 2048, 2048, kk * 1024, kk * 1024 + 1024,
                                    (tile & 15) * 128, (tile >> 4) * 64, lds);
}

// ---------------------------------------------------------------------------
// RoPE in-place on fp16, fp32 math. base = bl*rowStride + n*HD.
// ---------------------------------------------------------------------------
__global__ __launch_bounds__(256) void rope16(_Float16* __restrict__ x,
                                              const int* __restrict__ pos,
                                              int N, int rowStride) {
    size_t idx = (size_t)blockIdx.x * 256 + threadIdx.x;
    int h = (int)(idx & 63);
    size_t g = idx >> 6;
    int n = (int)(g % (size_t)N);
    size_t bl = g / (size_t)N;
    float p = (float)pos[bl];
    float ts = powf(10000.f, (float)h * (1.f / 64.f));
    float ang = p / ts;
    float s = sinf(ang), c = cosf(ang);
    size_t base = bl * (size_t)rowStride + (size_t)n * HD;
    float x1 = (float)x[base + h];
    float x2 = (float)x[base + h + 64];
    x[base + h]      = (_Float16)(x1 * c - x2 * s);
    x[base + h + 64] = (_Float16)(x2 * c + x1 * s);
}

// ---------------------------------------------------------------------------
// Flash attention (non-causal, scale=1.0, GQA group=4), all fp16, fp32 acc.
// Q:(B,T,NQ,HD); KV fused:(B,S,1024) — K at kn*HD, V at 512+kn*HD. O:(B,T,NQ,HD).
// Block = 128 thr (2 waves), 32 q-rows of one (b, q-head) -> 1024 blocks.
// One softmax pass per 64-col s-tile; __expf; lane-partial l (reduced at end).
// LDS: Ks 17.4K + Vt 18.4K + Ps 4.6K = 40.4 KB -> 4 blocks/CU.
// ---------------------------------------------------------------------------
__global__ __launch_bounds__(128) void attn_kernel(const _Float16* __restrict__ Q,
                                                   const _Float16* __restrict__ KV,
                                                   _Float16* __restrict__ O) {
    __shared__ __align__(16) _Float16 Ks[64][136];
    __shared__ __align__(16) _Float16 Vt[128][72];
    __shared__ __align__(16) _Float16 Ps[2][16][72];
    const int tid = threadIdx.x, lane = tid & 63, w = tid >> 6;
    const int quad = lane >> 4, l16 = lane & 15;
    const int blk = blockIdx.x;
    const int t0 = (blk & 31) * 32;       // T/32 = 32 q-tiles
    const int n  = (blk >> 5) & 15;       // q head
    const int b  = blk >> 9;              // batch
    const int kn = n >> 2;                // kv head

    half8 qf[4];
    #pragma unroll
    for (int kh = 0; kh < 4; ++kh)
        qf[kh] = load8_f16(&Q[(((size_t)b * T_SZ + t0 + w * 16 + l16) * NQ + n) * HD + kh * 32 + quad * 8]);

    f32x4 o_acc[8];
    #pragma unroll
    for (int i = 0; i < 8; ++i) o_acc[i] = (f32x4){0.f, 0.f, 0.f, 0.f};
    float m_row[4] = {-1e30f, -1e30f, -1e30f, -1e30f};
    float l_part[4] = {0.f, 0.f, 0.f, 0.f};

    for (int s0 = 0; s0 < S_SZ; s0 += 64) {
        __syncthreads();
        #pragma unroll
        for (int i = 0; i < 8; ++i) {
            int e = tid + i * 128;
            int r = e >> 4, c = (e & 15) * 8;
            *reinterpret_cast<half8*>(&Ks[r][c]) =
                load8_f16(&KV[(size_t)(b * S_SZ + s0 + r) * 1024 + kn * HD + c]);
            int vs = e & 63, vc = (e >> 6) * 8;
            half8 vv = load8_f16(&KV[(size_t)(b * S_SZ + s0 + vs) * 1024 + 512 + kn * HD + vc]);
            #pragma unroll
            for (int j = 0; j < 8; ++j) Vt[vc + j][vs] = vv[j];
        }
        __syncthreads();

        // ---- all 64 s-cols of scores: sf[sc*2+j2] ----
        f32x4 sf[4];
        #pragma unroll
        for (int i4 = 0; i4 < 4; ++i4) {
            const int sc = i4 >> 1, j2 = i4 & 1;
            f32x4 sa = (f32x4){0.f, 0.f, 0.f, 0.f};
            #pragma unroll
            for (int kh = 0; kh < 4; ++kh) {
                half8 bk = *reinterpret_cast<const half8*>(
                    &Ks[sc * 32 + j2 * 16 + l16][kh * 32 + quad * 8]);
                sa = __builtin_amdgcn_mfma_f32_16x16x32_f16(qf[kh], bk, sa, 0, 0, 0);
            }
            sf[i4] = sa;
        }
        // ---- single softmax pass over 64 cols (row = quad*4+r) ----
        #pragma unroll
        for (int r = 0; r < 4; ++r) {
            float mc = fmaxf(fmaxf(sf[0][r], sf[1][r]), fmaxf(sf[2][r], sf[3][r]));
            #pragma unroll
            for (int off = 1; off < 16; off <<= 1)
                mc = fmaxf(mc, __shfl_xor(mc, off, 64));
            float mn = fmaxf(m_row[r], mc);
            float alpha = __expf(m_row[r] - mn);
            m_row[r] = mn;
            float p0 = __expf(sf[0][r] - mn);
            float p1 = __expf(sf[1][r] - mn);
            float p2 = __expf(sf[2][r] - mn);
            float p3 = __expf(sf[3][r] - mn);
            l_part[r] = l_part[r] * alpha + (p0 + p1) + (p2 + p3);
            #pragma unroll
            for (int ht = 0; ht < 8; ++ht)
                o_acc[ht][r] *= alpha;
            Ps[w][quad * 4 + r][l16]      = (_Float16)p0;
            Ps[w][quad * 4 + r][16 + l16] = (_Float16)p1;
            Ps[w][quad * 4 + r][32 + l16] = (_Float16)p2;
            Ps[w][quad * 4 + r][48 + l16] = (_Float16)p3;
        }
        __builtin_amdgcn_wave_barrier();
        half8 ap0 = *reinterpret_cast<const half8*>(&Ps[w][l16][quad * 8]);
        half8 ap1 = *reinterpret_cast<const half8*>(&Ps[w][l16][32 + quad * 8]);
        __builtin_amdgcn_wave_barrier();
        // ---- O += P @ V (two 32-s chunks, 8 h-tiles) ----
        #pragma unroll
        for (int ht = 0; ht < 8; ++ht) {
            half8 bv0 = *reinterpret_cast<const half8*>(&Vt[ht * 16 + l16][quad * 8]);
            o_acc[ht] = __builtin_amdgcn_mfma_f32_16x16x32_f16(ap0, bv0, o_acc[ht], 0, 0, 0);
        }
        #pragma unroll
        for (int ht = 0; ht < 8; ++ht) {
            half8 bv1 = *reinterpret_cast<const half8*>(&Vt[ht * 16 + l16][32 + quad * 8]);
            o_acc[ht] = __builtin_amdgcn_mfma_f32_16x16x32_f16(ap1, bv1, o_acc[ht], 0, 0, 0);
        }
    }

    // ---- final cross-lane l reduction + epilogue ----
    float inv_l[4];
    #pragma unroll
    for (int r = 0; r < 4; ++r) {
        float l = l_part[r];
        #pragma unroll
        for (int off = 1; off < 16; off <<= 1)
            l += __shfl_xor(l, off, 64);
        inv_l[r] = 1.f / fmaxf(l, 1e-30f);
    }
    #pragma unroll
    for (int ht = 0; ht < 8; ++ht)
        #pragma unroll
        for (int r = 0; r < 4; ++r)
            O[(((size_t)b * T_SZ + t0 + w * 16 + quad * 4 + r) * NQ + n) * HD + ht * 16 + l16] =
                (_Float16)(o_acc[ht][r] * inv_l[r]);
}

// ---------------------------------------------------------------------------
extern "C" void kernel_launch(void* const* d_in, const int* in_sizes, int n_in,
                              void* d_out, int out_size, void* d_ws, size_t ws_size,
                              hipStream_t stream) {
    const float* Xq   = (const float*)d_in[0];
    const float* Xkv  = (const float*)d_in[1];
    const int*   qpos = (const int*)d_in[2];
    const int*   kpos = (const int*)d_in[3];
    const float* Wq   = (const float*)d_in[4];
    const float* Wk   = (const float*)d_in[5];
    const float* Wv   = (const float*)d_in[6];
    const float* Wo   = (const float*)d_in[7];
    float* out = (float*)d_out;

    // workspace packing with lifetime reuse (as round 7)
    const size_t SZ8 = 8388608;
    uint8_t* ws = (uint8_t*)d_ws;
    _Float16* Xq16  = (_Float16*)(ws);
    _Float16* Xkv16 = (_Float16*)(ws + SZ8);
    _Float16* WqT   = (_Float16*)(ws + 2 * SZ8);
    _Float16* WkvT  = (_Float16*)(ws + 3 * SZ8);
    _Float16* Qh    = (_Float16*)(ws + 3 * SZ8 + 4194304);
    _Float16* Ah  = Xq16;   // attn out reuses Xq16 (dead after proj)
    _Float16* WoT = Xkv16;  // WoT reuses Xkv16 (dead after proj)
    _Float16* KVh = WqT;    // KV reuses WqT (dead after proj)

    dim3 blk(256);
    // zero the atomic-accumulated output
    hipMemsetAsync(out, 0, (size_t)B_SZ * T_SZ * DOUT * sizeof(float), stream);
    // pre-passes
    convert_f32_f16<<<2048, blk, 0, stream>>>(Xq, Xq16);
    convert_f32_f16<<<2048, blk, 0, stream>>>(Xkv, Xkv16);
    transpose_f32_f16<<<dim3(32, 32), blk, 0, stream>>>(Wq, WqT, 2048, 2048);
    transpose_f32_f16<<<dim3(8, 32), blk, 0, stream>>>(Wk, WkvT, 2048, 512);
    transpose_f32_f16<<<dim3(8, 32), blk, 0, stream>>>(Wv, WkvT + (size_t)512 * 2048, 2048, 512);
    // fused Q + KV projection (768 blocks, 3/CU)
    proj_fused<<<768, blk, 0, stream>>>(Xq16, WqT, Qh, Xkv16, WkvT, KVh);
    // Wo transpose into Xkv16's slot (dead after proj)
    transpose_f32_f16<<<dim3(32, 32), blk, 0, stream>>>(Wo, WoT, 2048, 2048);
    // RoPE on Q and on K-half of KV
    rope16<<<8192, blk, 0, stream>>>(Qh, qpos, NQ, NQ * HD);
    rope16<<<2048, blk, 0, stream>>>(KVh, kpos, NKV, 1024);
    // GQA flash attention (1024 blocks x 128 thr)
    attn_kernel<<<1024, dim3(128), 0, stream>>>(Qh, KVh, Ah);
    // output projection: split-K=2, atomic fp32 (1024 blocks)
    gemm_splitk<<<1024, blk, 0, stream>>>(Ah, WoT, out);
}

// Round 9
// 336.932 us; speedup vs baseline: 1.5420x; 1.0417x over previous
//
#include <hip/hip_runtime.h>
#include <hip/hip_bf16.h>
#include <math.h>
#include <stdint.h>

// Problem constants (fixed by the reference)
#define B_SZ 2
#define T_SZ 1024
#define S_SZ 1024
#define NQ 16
#define NKV 4
#define HD 128
#define DQ 2048
#define DKV 2048
#define DOUT 2048

typedef _Float16 half8 __attribute__((ext_vector_type(8)));
typedef _Float16 half4 __attribute__((ext_vector_type(4)));
typedef float f32x4 __attribute__((ext_vector_type(4)));

__device__ __forceinline__ half8 load8_f16(const _Float16* p) {
    return *reinterpret_cast<const half8*>(p);
}

// ---- async global->LDS, 16 B per lane; lds base must be wave-uniform ------
__device__ __forceinline__ void stage16(const _Float16* g, _Float16* l, int lane) {
#if __has_builtin(__builtin_amdgcn_global_load_lds)
    __builtin_amdgcn_global_load_lds(
        (const __attribute__((address_space(1))) uint32_t*)g,
        (__attribute__((address_space(3))) uint32_t*)l, 16, 0, 0);
#else
    *reinterpret_cast<half8*>(l + lane * 8) = *reinterpret_cast<const half8*>(g);
#endif
}

// ---------------------------------------------------------------------------
// device helpers for fused prep kernels (block-uniform routing)
// ---------------------------------------------------------------------------
__device__ __forceinline__ void conv_blk(const float* __restrict__ in,
                                         _Float16* __restrict__ out, int vb) {
    size_t i = ((size_t)vb * 256 + threadIdx.x) * 8;
    float4 a = *reinterpret_cast<const float4*>(in + i);
    float4 b = *reinterpret_cast<const float4*>(in + i + 4);
    half8 r;
    r[0] = (_Float16)a.x; r[1] = (_Float16)a.y; r[2] = (_Float16)a.z; r[3] = (_Float16)a.w;
    r[4] = (_Float16)b.x; r[5] = (_Float16)b.y; r[6] = (_Float16)b.z; r[7] = (_Float16)b.w;
    *reinterpret_cast<half8*>(out + i) = r;
}

__device__ __forceinline__ void tr_blk(const float* __restrict__ in,
                                       _Float16* __restrict__ out,
                                       int R, int C, int bx, int by,
                                       _Float16 (*tile)[72]) {
    const int tx = threadIdx.x & 15, ty = threadIdx.x >> 4;
    const int r0 = by * 64, c0 = bx * 64;
    #pragma unroll
    for (int i = 0; i < 4; ++i) {
        int r = ty + i * 16;
        float4 v = *reinterpret_cast<const float4*>(&in[(size_t)(r0 + r) * C + c0 + tx * 4]);
        tile[r][tx * 4 + 0] = (_Float16)v.x;
        tile[r][tx * 4 + 1] = (_Float16)v.y;
        tile[r][tx * 4 + 2] = (_Float16)v.z;
        tile[r][tx * 4 + 3] = (_Float16)v.w;
    }
    __syncthreads();
    #pragma unroll
    for (int i = 0; i < 4; ++i) {
        int oc = ty + i * 16;
        half4 v;
        v[0] = tile[tx * 4 + 0][oc];
        v[1] = tile[tx * 4 + 1][oc];
        v[2] = tile[tx * 4 + 2][oc];
        v[3] = tile[tx * 4 + 3][oc];
        *reinterpret_cast<half4*>(&out[(size_t)(c0 + oc) * R + r0 + tx * 4]) = v;
    }
}

__device__ __forceinline__ void rope_blk(_Float16* __restrict__ x,
                                         const int* __restrict__ pos,
                                         int N, int rowStride, int vb) {
    size_t idx = (size_t)vb * 256 + threadIdx.x;
    int h = (int)(idx & 63);
    size_t g = idx >> 6;
    int n = (int)(g % (size_t)N);
    size_t bl = g / (size_t)N;
    float p = (float)pos[bl];
    float ts = powf(10000.f, (float)h * (1.f / 64.f));
    float ang = p / ts;
    float s = sinf(ang), c = cosf(ang);
    size_t base = bl * (size_t)rowStride + (size_t)n * HD;
    float x1 = (float)x[base + h];
    float x2 = (float)x[base + h + 64];
    x[base + h]      = (_Float16)(x1 * c - x2 * s);
    x[base + h + 64] = (_Float16)(x2 * c + x1 * s);
}

// prep1: convert Xq, Xkv; transpose Wq, Wk, Wv.  5632 blocks.
__global__ __launch_bounds__(256) void prep1(const float* __restrict__ Xq, _Float16* __restrict__ Xq16,
                                             const float* __restrict__ Xkv, _Float16* __restrict__ Xkv16,
                                             const float* __restrict__ Wq, _Float16* __restrict__ WqT,
                                             const float* __restrict__ Wk, const float* __restrict__ Wv,
                                             _Float16* __restrict__ WkvT) {
    __shared__ _Float16 tile[64][72];
    int bx = blockIdx.x;
    if (bx < 2048) { conv_blk(Xq, Xq16, bx); return; }
    bx -= 2048;
    if (bx < 2048) { conv_blk(Xkv, Xkv16, bx); return; }
    bx -= 2048;
    if (bx < 1024) { tr_blk(Wq, WqT, 2048, 2048, bx & 31, bx >> 5, tile); return; }
    bx -= 1024;
    if (bx < 256) { tr_blk(Wk, WkvT, 2048, 512, bx & 7, bx >> 3, tile); return; }
    bx -= 256;
    tr_blk(Wv, WkvT + (size_t)512 * 2048, 2048, 512, bx & 7, bx >> 3, tile);
}

// prep2: transpose Wo (into Xkv16's slot); RoPE on Q and KV.  11264 blocks.
__global__ __launch_bounds__(256) void prep2(const float* __restrict__ Wo, _Float16* __restrict__ WoT,
                                             _Float16* __restrict__ Qh, const int* __restrict__ qpos,
                                             _Float16* __restrict__ KVh, const int* __restrict__ kpos) {
    __shared__ _Float16 tile[64][72];
    int bx = blockIdx.x;
    if (bx < 1024) { tr_blk(Wo, WoT, 2048, 2048, bx & 31, bx >> 5, tile); return; }
    bx -= 1024;
    if (bx < 8192) { rope_blk(Qh, qpos, NQ, NQ * HD, bx); return; }
    bx -= 8192;
    rope_blk(KVh, kpos, NKV, 1024, bx);
}

// ---------------------------------------------------------------------------
// GEMM tile body: C[bm:+BM][bn:+BN] (+)= A[.][kbeg:kend] * Bt[.][kbeg:kend]^T
// A,Bt fp16 row-major, row stride K. 4 waves, wave grid 2x2. BK=64: one
// staging round (global_load_lds w16, fragment-order LDS, conflict-free)
// feeds two 32-k MFMA steps -> 16 MFMA/wave per barrier.
// LDS layout: A elem (kb,r) at (kb*BM+r)*8, kb in [0,8); B at BM*64 offset.
// ---------------------------------------------------------------------------
template <int BM, int BN, bool ATOMIC, typename TC>
__device__ __forceinline__ void gemm_tile(const _Float16* __restrict__ A,
                                          const _Float16* __restrict__ Bt,
                                          TC* __restrict__ C,
                                          int N, int K, int kbeg, int kend,
                                          int bm, int bn, _Float16* lds) {
    constexpr int ASEG = BM / 8, BSEG = BN / 8, TSEG = ASEG + BSEG, PSEG = TSEG / 4;
    const int tid = threadIdx.x, lane = tid & 63, w = tid >> 6;
    const int quad = lane >> 4, l16 = lane & 15;
    constexpr int WM = BM / 2, WN = BN / 2, MI = WM / 16, NI = WN / 16;
    const int wm = (w >> 1) * WM, wn = (w & 1) * WN;

    const _Float16* gp[PSEG];
    _Float16* lp[PSEG];
    #pragma unroll
    for (int p = 0; p < PSEG; ++p) {
        int s = w + p * 4;
        if (s < ASEG) {
            int li = s * 64 + lane;          // 8-el chunk index = kb*BM + r
            int kb = li / BM, r = li % BM;
            gp[p] = A + (size_t)(bm + r) * K + kbeg + kb * 8;
        } else {
            int li = (s - ASEG) * 64 + lane;
            int kb = li / BN, r = li % BN;
            gp[p] = Bt + (size_t)(bn + r) * K + kbeg + kb * 8;
        }
        lp[p] = lds + s * 512;
    }

    f32x4 acc[MI][NI];
    #pragma unroll
    for (int i = 0; i < MI; ++i)
        #pragma unroll
        for (int j = 0; j < NI; ++j)
            acc[i][j] = (f32x4){0.f, 0.f, 0.f, 0.f};

    const int nsteps = (kend - kbeg) >> 6;
    for (int it = 0; it < nsteps; ++it) {
        const int ko = it * 64;
        __syncthreads();
        #pragma unroll
        for (int p = 0; p < PSEG; ++p)
            stage16(gp[p] + ko, lp[p], lane);
        __syncthreads();

        #pragma unroll
        for (int h = 0; h < 2; ++h) {        // two 32-k MFMA steps per round
            half8 af[MI], bf[NI];
            #pragma unroll
            for (int i = 0; i < MI; ++i)
                af[i] = *reinterpret_cast<const half8*>(
                    &lds[((h * 4 + quad) * BM + wm + 16 * i + l16) * 8]);
            #pragma unroll
            for (int j = 0; j < NI; ++j)
                bf[j] = *reinterpret_cast<const half8*>(
                    &lds[BM * 64 + ((h * 4 + quad) * BN + wn + 16 * j + l16) * 8]);
            #pragma unroll
            for (int i = 0; i < MI; ++i)
                #pragma unroll
                for (int j = 0; j < NI; ++j)
                    acc[i][j] = __builtin_amdgcn_mfma_f32_16x16x32_f16(af[i], bf[j], acc[i][j], 0, 0, 0);
        }
    }

    #pragma unroll
    for (int i = 0; i < MI; ++i)
        #pragma unroll
        for (int j = 0; j < NI; ++j)
            #pragma unroll
            for (int r = 0; r < 4; ++r) {
                size_t idx = (size_t)(bm + wm + 16 * i + quad * 4 + r) * N + bn + wn + 16 * j + l16;
                if (ATOMIC) atomicAdd((float*)&C[idx], acc[i][j][r]);
                else        C[idx] = (TC)acc[i][j][r];
            }
}

// Fused Q-proj + KV-proj: blocks [0,512) -> Q (N=2048); [512,768) -> KV (N=1024).
__global__ __launch_bounds__(256) void proj_fused(const _Float16* __restrict__ Xq,
                                                  const _Float16* __restrict__ WqT,
                                                  _Float16* __restrict__ Qh,
                                                  const _Float16* __restrict__ Xkv,
                                                  const _Float16* __restrict__ WkvT,
                                                  _Float16* __restrict__ KVh) {
    __shared__ __align__(16) _Float16 lds[(128 + 64) * 64];
    int bx = blockIdx.x;
    if (bx < 512) {
        gemm_tile<128, 64, false, _Float16>(Xq, WqT, Qh, 2048, 2048, 0, 2048,
                                            (bx & 15) * 128, (bx >> 4) * 64, lds);
    } else {
        bx -= 512;
        gemm_tile<128, 64, false, _Float16>(Xkv, WkvT, KVh, 1024, 2048, 0, 2048,
                                            (bx & 15) * 128, (bx >> 4) * 64, lds);
    }
}

// Out-proj, split-K=2, fp32 atomic accumulate into pre-zeroed C.
__global__ __launch_bounds__(256) void gemm_splitk(const _Float16* __restrict__ A,
                                                   const _Float16* __restrict__ Bt,
                                                   float* __restrict__ C) {
    __shared__ __align__(16) _Float16 lds[(128 + 64) * 64];
    const int bx = blockIdx.x;
    const int tile = bx & 511, kk = bx >> 9;
    gemm_tile<128, 64, true, float>(A, Bt, C, 2048, 2048, kk * 1024, kk * 1024 + 1024,
                                    (tile & 15) * 128, (tile >> 4) * 64, lds);
}

// ---------------------------------------------------------------------------
// Flash attention (non-causal, scale=1.0, GQA group=4), all fp16, fp32 acc.
// Q:(B,T,NQ,HD); KV fused:(B,S,1024) — K at kn*HD, V at 512+kn*HD. O:(B,T,NQ,HD).
// Block = 128 thr (2 waves), 32 q-rows of one (b, q-head) -> 1024 blocks.
// ---------------------------------------------------------------------------
__global__ __launch_bounds__(128) void attn_kernel(const _Float16* __restrict__ Q,
                                                   const _Float16* __restrict__ KV,
                                                   _Float16* __restrict__ O) {
    __shared__ __align__(16) _Float16 Ks[64][136];
    __shared__ __align__(16) _Float16 Vt[128][72];
    __shared__ __align__(16) _Float16 Ps[2][16][72];
    const int tid = threadIdx.x, lane = tid & 63, w = tid >> 6;
    const int quad = lane >> 4, l16 = lane & 15;
    const int blk = blockIdx.x;
    const int t0 = (blk & 31) * 32;
    const int n  = (blk >> 5) & 15;
    const int b  = blk >> 9;
    const int kn = n >> 2;

    half8 qf[4];
    #pragma unroll
    for (int kh = 0; kh < 4; ++kh)
        qf[kh] = load8_f16(&Q[(((size_t)b * T_SZ + t0 + w * 16 + l16) * NQ + n) * HD + kh * 32 + quad * 8]);

    f32x4 o_acc[8];
    #pragma unroll
    for (int i = 0; i < 8; ++i) o_acc[i] = (f32x4){0.f, 0.f, 0.f, 0.f};
    float m_row[4] = {-1e30f, -1e30f, -1e30f, -1e30f};
    float l_part[4] = {0.f, 0.f, 0.f, 0.f};

    for (int s0 = 0; s0 < S_SZ; s0 += 64) {
        __syncthreads();
        #pragma unroll
        for (int i = 0; i < 8; ++i) {
            int e = tid + i * 128;
            int r = e >> 4, c = (e & 15) * 8;
            *reinterpret_cast<half8*>(&Ks[r][c]) =
                load8_f16(&KV[(size_t)(b * S_SZ + s0 + r) * 1024 + kn * HD + c]);
            int vs = e & 63, vc = (e >> 6) * 8;
            half8 vv = load8_f16(&KV[(size_t)(b * S_SZ + s0 + vs) * 1024 + 512 + kn * HD + vc]);
            #pragma unroll
            for (int j = 0; j < 8; ++j) Vt[vc + j][vs] = vv[j];
        }
        __syncthreads();

        f32x4 sf[4];
        #pragma unroll
        for (int i4 = 0; i4 < 4; ++i4) {
            const int sc = i4 >> 1, j2 = i4 & 1;
            f32x4 sa = (f32x4){0.f, 0.f, 0.f, 0.f};
            #pragma unroll
            for (int kh = 0; kh < 4; ++kh) {
                half8 bk = *reinterpret_cast<const half8*>(
                    &Ks[sc * 32 + j2 * 16 + l16][kh * 32 + quad * 8]);
                sa = __builtin_amdgcn_mfma_f32_16x16x32_f16(qf[kh], bk, sa, 0, 0, 0);
            }
            sf[i4] = sa;
        }
        #pragma unroll
        for (int r = 0; r < 4; ++r) {
            float mc = fmaxf(fmaxf(sf[0][r], sf[1][r]), fmaxf(sf[2][r], sf[3][r]));
            #pragma unroll
            for (int off = 1; off < 16; off <<= 1)
                mc = fmaxf(mc, __shfl_xor(mc, off, 64));
            float mn = fmaxf(m_row[r], mc);
            float alpha = __expf(m_row[r] - mn);
            m_row[r] = mn;
            float p0 = __expf(sf[0][r] - mn);
            float p1 = __expf(sf[1][r] - mn);
            float p2 = __expf(sf[2][r] - mn);
            float p3 = __expf(sf[3][r] - mn);
            l_part[r] = l_part[r] * alpha + (p0 + p1) + (p2 + p3);
            #pragma unroll
            for (int ht = 0; ht < 8; ++ht)
                o_acc[ht][r] *= alpha;
            Ps[w][quad * 4 + r][l16]      = (_Float16)p0;
            Ps[w][quad * 4 + r][16 + l16] = (_Float16)p1;
            Ps[w][quad * 4 + r][32 + l16] = (_Float16)p2;
            Ps[w][quad * 4 + r][48 + l16] = (_Float16)p3;
        }
        __builtin_amdgcn_wave_barrier();
        half8 ap0 = *reinterpret_cast<const half8*>(&Ps[w][l16][quad * 8]);
        half8 ap1 = *reinterpret_cast<const half8*>(&Ps[w][l16][32 + quad * 8]);
        __builtin_amdgcn_wave_barrier();
        #pragma unroll
        for (int ht = 0; ht < 8; ++ht) {
            half8 bv0 = *reinterpret_cast<const half8*>(&Vt[ht * 16 + l16][quad * 8]);
            o_acc[ht] = __builtin_amdgcn_mfma_f32_16x16x32_f16(ap0, bv0, o_acc[ht], 0, 0, 0);
        }
        #pragma unroll
        for (int ht = 0; ht < 8; ++ht) {
            half8 bv1 = *reinterpret_cast<const half8*>(&Vt[ht * 16 + l16][32 + quad * 8]);
            o_acc[ht] = __builtin_amdgcn_mfma_f32_16x16x32_f16(ap1, bv1, o_acc[ht], 0, 0, 0);
        }
    }

    float inv_l[4];
    #pragma unroll
    for (int r = 0; r < 4; ++r) {
        float l = l_part[r];
        #pragma unroll
        for (int off = 1; off < 16; off <<= 1)
            l += __shfl_xor(l, off, 64);
        inv_l[r] = 1.f / fmaxf(l, 1e-30f);
    }
    #pragma unroll
    for (int ht = 0; ht < 8; ++ht)
        #pragma unroll
        for (int r = 0; r < 4; ++r)
            O[(((size_t)b * T_SZ + t0 + w * 16 + quad * 4 + r) * NQ + n) * HD + ht * 16 + l16] =
                (_Float16)(o_acc[ht][r] * inv_l[r]);
}

// ---------------------------------------------------------------------------
extern "C" void kernel_launch(void* const* d_in, const int* in_sizes, int n_in,
                              void* d_out, int out_size, void* d_ws, size_t ws_size,
                              hipStream_t stream) {
    const float* Xq   = (const float*)d_in[0];
    const float* Xkv  = (const float*)d_in[1];
    const int*   qpos = (const int*)d_in[2];
    const int*   kpos = (const int*)d_in[3];
    const float* Wq   = (const float*)d_in[4];
    const float* Wk   = (const float*)d_in[5];
    const float* Wv   = (const float*)d_in[6];
    const float* Wo   = (const float*)d_in[7];
    float* out = (float*)d_out;

    // workspace packing with lifetime reuse
    const size_t SZ8 = 8388608;
    uint8_t* ws = (uint8_t*)d_ws;
    _Float16* Xq16  = (_Float16*)(ws);
    _Float16* Xkv16 = (_Float16*)(ws + SZ8);
    _Float16* WqT   = (_Float16*)(ws + 2 * SZ8);
    _Float16* WkvT  = (_Float16*)(ws + 3 * SZ8);
    _Float16* Qh    = (_Float16*)(ws + 3 * SZ8 + 4194304);
    _Float16* Ah  = Xq16;   // attn out reuses Xq16 (dead after proj)
    _Float16* WoT = Xkv16;  // WoT reuses Xkv16 (dead after proj)
    _Float16* KVh = WqT;    // KV reuses WqT (dead after proj)

    dim3 blk(256);
    // zero the atomic-accumulated output
    hipMemsetAsync(out, 0, (size_t)B_SZ * T_SZ * DOUT * sizeof(float), stream);
    // prep1: converts + Wq/Wk/Wv transposes (one launch)
    prep1<<<5632, blk, 0, stream>>>(Xq, Xq16, Xkv, Xkv16, Wq, WqT, Wk, Wv, WkvT);
    // fused Q + KV projection (768 blocks, 3/CU, BK=64)
    proj_fused<<<768, blk, 0, stream>>>(Xq16, WqT, Qh, Xkv16, WkvT, KVh);
    // prep2: Wo transpose + RoPE on Q and KV (one launch)
    prep2<<<11264, blk, 0, stream>>>(Wo, WoT, Qh, qpos, KVh, kpos);
    // GQA flash attention (1024 blocks x 128 thr)
    attn_kernel<<<1024, dim3(128), 0, stream>>>(Qh, KVh, Ah);
    // output projection: split-K=2, atomic fp32 (1024 blocks, BK=64)
    gemm_splitk<<<1024, blk, 0, stream>>>(Ah, WoT, out);
}